// Round 16
// baseline (396.238 us; speedup 1.0000x reference)
//
#include <hip/hip_runtime.h>
#include <hip/hip_bf16.h>

// ---------------------------------------------------------------------------
// KascadeReuseAttention: B=2,S=4096,H=16,D=128, TILE=128, T=32, TOPK=7(+local)
// R16: gemm256 switched to v_mfma_f32_32x32x16_bf16 (2382 vs 2075 TF ubench,
// half the MFMA instruction count). Same R15 skeleton: BK=64, 2-slot, one
// barrier/phase, M-fastest chunks. Epilogues re-derived for 32x32 C-layout
// (col=l&31, row=(reg&3)+8*(reg>>2)+4*(l>>5)). attn/prep = R15.
// ---------------------------------------------------------------------------

typedef __bf16 bf16_t;
using bf16x8 = __attribute__((ext_vector_type(8))) __bf16;
using bf16x4 = __attribute__((ext_vector_type(4))) __bf16;
using f32x4  = __attribute__((ext_vector_type(4))) float;
using f32x16 = __attribute__((ext_vector_type(16))) float;

typedef const __attribute__((address_space(1))) void* gas_ptr;
typedef __attribute__((address_space(3))) void* las_ptr;

__device__ __forceinline__ void async_copy16(const void* g, void* l) {
  __builtin_amdgcn_global_load_lds((gas_ptr)g, (las_ptr)l, 16, 0, 0);
}

__device__ __forceinline__ f32x4 mfma16x16x32(bf16x8 a, bf16x8 b, f32x4 c) {
  return __builtin_amdgcn_mfma_f32_16x16x32_bf16(a, b, c, 0, 0, 0);
}
__device__ __forceinline__ f32x16 mfma32x32x16(bf16x8 a, bf16x8 b, f32x16 c) {
  return __builtin_amdgcn_mfma_f32_32x32x16_bf16(a, b, c, 0, 0, 0);
}

#define SBAR0() __builtin_amdgcn_sched_barrier(0)

// -------- prep: weight transpose x4 + x f32->bf16, one dispatch -------------
__global__ void prep_kernel(const float* __restrict__ x, const float* __restrict__ wq,
                            const float* __restrict__ wk, const float* __restrict__ wv,
                            const float* __restrict__ wo, bf16_t* __restrict__ xb,
                            bf16_t* __restrict__ wcat, bf16_t* __restrict__ wot) {
  __shared__ bf16_t t[64][66];
  const int bidx = blockIdx.x;
  if (bidx >= 4096) {
    int idx = (bidx - 4096) * 256 + threadIdx.x;
    float4 v = ((const float4*)x)[idx];
    bf16x4 r;
    r.x = (bf16_t)v.x; r.y = (bf16_t)v.y; r.z = (bf16_t)v.z; r.w = (bf16_t)v.w;
    ((bf16x4*)xb)[idx] = r;
    return;
  }
  const int z = bidx >> 10, bt = bidx & 1023;
  const float* W = (z == 0) ? wq : (z == 1) ? wk : (z == 2) ? wv : wo;
  bf16_t* Wt = (z == 3) ? wot : (wcat + (size_t)z * 2048 * 2048);
  const int r0 = (bt >> 5) * 64, c0 = (bt & 31) * 64;
  const int tx = threadIdx.x & 63, ty = threadIdx.x >> 6;
  #pragma unroll
  for (int i = 0; i < 16; ++i) {
    int r = ty + 4 * i;
    t[r][tx] = (bf16_t)W[(size_t)(r0 + r) * 2048 + c0 + tx];
  }
  __syncthreads();
  #pragma unroll
  for (int i = 0; i < 16; ++i) {
    int n = ty + 4 * i;
    Wt[(size_t)(c0 + n) * 2048 + r0 + tx] = t[tx][n];
  }
}

// ---------------- GEMM 256x256 pipelined, 32x32x16 MFMA ---------------------
// 8 waves as 4M x 2N; wave tile 64Mx128N = 2 x 4 frags of 32x32.
// LDS: 2-slot dbuf of A[256][64]+B[256][64] bf16 panels (128KiB); rows of
// 8x16B chunks, swizzle ch ^= (row&7) (write-source + read, bijective).
// Operand frags: lane c31=l&31 -> row; khalf=l>>5 -> 8-elem k-half;
// K-step ks (k=ks*16): chunk = ks*2+khalf. C/D: col=c31,
// row=(reg&3)+8*(reg>>2)+4*khalf [m74/m101].
// Phase (32, BK=64): {ks0/ks1 frags (12 ds_read) | STAGE(phi+1) | 16 MFMA |
// ks2/ks3 frags | 16 MFMA | vmcnt(0) | raw s_barrier}.
// mode 0: f32 C row-major (nb=8), coalesced via per-wave LDS scratch.
// mode 1: fused QKV (nb=24): Q,K rope'd bf16 [B,H,S,D]; V -> V^T [B,H,D,S].
__global__ __launch_bounds__(512, 2) void gemm256(
    const bf16_t* __restrict__ A, const bf16_t* __restrict__ Bt,
    int nb, int mode, float* __restrict__ Cf,
    bf16_t* __restrict__ outQ, bf16_t* __restrict__ outK,
    bf16_t* __restrict__ outVT,
    const float* __restrict__ cosT, const float* __restrict__ sinT)
{
  __shared__ bf16_t Apan[2][16384];   // [256 rows][64 k] bf16 = 32KB per slot
  __shared__ bf16_t Bpan[2][16384];
  const int bid = blockIdx.x;
  const int cpx = gridDim.x >> 3;
  const int swz = (bid & 7) * cpx + (bid >> 3);   // XCD-chunked (grid%8==0)
  const int RM = cpx / nb;                        // M-rows per chunk
  const int bm = ((swz / cpx) * RM + (swz % RM)) * 256;   // M fastest in chunk
  const int bn = ((swz % cpx) / RM) * 256;
  const int tid = threadIdx.x;
  const int w = tid >> 6, l = tid & 63;
  const int wr = w >> 1, wc = w & 1;              // 4M x 2N
  const int c31 = l & 31, khalf = l >> 5;

  const bf16_t* aS[4];
  const bf16_t* bS[4];
  int dst[4];
  #pragma unroll
  for (int i = 0; i < 4; ++i) {
    int c = tid + i * 512;
    int row = c >> 3, ch = c & 7;
    int sc = (ch ^ (row & 7)) * 8;
    aS[i] = A  + (size_t)(bm + row) * 2048 + sc;
    bS[i] = Bt + (size_t)(bn + row) * 2048 + sc;
    dst[i] = c * 16;
  }

  // frag-read byte offsets: [ks][frag] within a [256][64] panel
  int aOff[4][2], bOff[4][4];
  #pragma unroll
  for (int ks = 0; ks < 4; ++ks) {
    int chb = ks * 2 + khalf;
    #pragma unroll
    for (int am = 0; am < 2; ++am) {
      int R = wr * 64 + am * 32 + c31;
      aOff[ks][am] = R * 128 + ((chb ^ (R & 7)) << 4);
    }
    #pragma unroll
    for (int bnf = 0; bnf < 4; ++bnf) {
      int R = wc * 128 + bnf * 32 + c31;
      bOff[ks][bnf] = R * 128 + ((chb ^ (R & 7)) << 4);
    }
  }

  f32x16 acc[2][4];
  #pragma unroll
  for (int m = 0; m < 2; ++m)
    #pragma unroll
    for (int n = 0; n < 4; ++n)
      #pragma unroll
      for (int j = 0; j < 16; ++j) acc[m][n][j] = 0.f;

  auto STAGE = [&](int t) {        // stage K-tile t (64 wide) into slot t&1
    const int slot = t & 1;
    const int kb = t * 64;
    char* dA = (char*)&Apan[slot][0];
    char* dB = (char*)&Bpan[slot][0];
    #pragma unroll
    for (int i = 0; i < 4; ++i) {
      async_copy16(aS[i] + kb, dA + dst[i]);
      async_copy16(bS[i] + kb, dB + dst[i]);
    }
  };

  STAGE(0);
  __syncthreads();   // prologue: tile 0 landed (full drain, once)

  #pragma unroll 1
  for (int phi = 0; phi < 32; ++phi) {
    const int slot = phi & 1;
    const char* pa = (const char*)&Apan[slot][0];
    const char* pb = (const char*)&Bpan[slot][0];

    // ks 0,1 fragments
    bf16x8 aF0[2][2], bF0[2][4];
    #pragma unroll
    for (int ks = 0; ks < 2; ++ks) {
      #pragma unroll
      for (int am = 0; am < 2; ++am) aF0[ks][am] = *(const bf16x8*)(pa + aOff[ks][am]);
      #pragma unroll
      for (int n = 0; n < 4; ++n)   bF0[ks][n]  = *(const bf16x8*)(pb + bOff[ks][n]);
    }
    if (phi < 31) STAGE(phi + 1);
    __builtin_amdgcn_s_setprio(1);
    #pragma unroll
    for (int ks = 0; ks < 2; ++ks)
      #pragma unroll
      for (int m = 0; m < 2; ++m)
        #pragma unroll
        for (int n = 0; n < 4; ++n)
          acc[m][n] = mfma32x32x16(aF0[ks][m], bF0[ks][n], acc[m][n]);
    __builtin_amdgcn_s_setprio(0);

    // ks 2,3 fragments
    bf16x8 aF1[2][2], bF1[2][4];
    #pragma unroll
    for (int ks = 0; ks < 2; ++ks) {
      #pragma unroll
      for (int am = 0; am < 2; ++am) aF1[ks][am] = *(const bf16x8*)(pa + aOff[2 + ks][am]);
      #pragma unroll
      for (int n = 0; n < 4; ++n)   bF1[ks][n]  = *(const bf16x8*)(pb + bOff[2 + ks][n]);
    }
    __builtin_amdgcn_s_setprio(1);
    #pragma unroll
    for (int ks = 0; ks < 2; ++ks)
      #pragma unroll
      for (int m = 0; m < 2; ++m)
        #pragma unroll
        for (int n = 0; n < 4; ++n)
          acc[m][n] = mfma32x32x16(aF1[ks][m], bF1[ks][n], acc[m][n]);
    __builtin_amdgcn_s_setprio(0);

    asm volatile("s_waitcnt vmcnt(0)" ::: "memory");
    SBAR0();
    __builtin_amdgcn_s_barrier();
    SBAR0();
  }

  if (mode == 0) {
    // coalesced f32 store via per-wave 16KB LDS scratch (panels dead).
    // half h == m: rows m*32 + r32, r32 = (j&3)+8*(j>>2)+4*khalf in 0..31.
    float* S = (w < 4) ? (float*)((char*)&Apan[0][0] + w * 16384)
                       : (float*)((char*)&Bpan[0][0] + (w - 4) * 16384);
    #pragma unroll
    for (int m = 0; m < 2; ++m) {
      #pragma unroll
      for (int n = 0; n < 4; ++n)
        #pragma unroll
        for (int j = 0; j < 16; ++j) {
          int r32 = (j & 3) + 8 * (j >> 2) + 4 * khalf;
          S[r32 * 128 + n * 32 + c31] = acc[m][n][j];
        }
      #pragma unroll
      for (int r2 = 0; r2 < 32; ++r2) {
        float2 v = *(const float2*)&S[r2 * 128 + l * 2];
        int row = bm + wr * 64 + m * 32 + r2;
        *(float2*)&Cf[(size_t)row * 2048 + bn + wc * 128 + l * 2] = v;
      }
    }
    return;
  }

  // ---- fused QKV epilogue (32x32 C-layout) ----
  const int colbase = bn + wc * 128;          // wave-uniform, multiple of 128
  const int proj = colbase >> 11;             // 0=Q 1=K 2=V
  const int hh = (colbase & 2047) >> 7;
  const int b_ = bm >> 12;                    // block never crosses batch bdry
  if (proj == 2) {
    // V^T [BH*128 d][4096 s]: j&3 = 4 consecutive s -> bf16x4 store
    #pragma unroll
    for (int m = 0; m < 2; ++m) {
      int row0 = ((bm + wr * 64 + m * 32) & 4095) + 4 * khalf;
      #pragma unroll
      for (int n = 0; n < 4; ++n) {
        int d_ = n * 32 + c31;
        size_t dbase = (((size_t)(b_ * 16 + hh)) * 128 + d_) * 4096;
        #pragma unroll
        for (int g = 0; g < 4; ++g) {
          bf16x4 pkv;
          #pragma unroll
          for (int q = 0; q < 4; ++q) pkv[q] = (bf16_t)acc[m][n][g * 4 + q];
          *(bf16x4*)&outVT[dbase + row0 + 8 * g] = pkv;
        }
      }
    }
  } else {
    bf16_t* dst_ = proj ? outK : outQ;
    size_t hbase = ((size_t)(b_ * 16 + hh)) * 4096;
    #pragma unroll
    for (int m = 0; m < 2; ++m) {
      int s0 = ((bm + wr * 64 + m * 32) & 4095) + 4 * khalf;
      #pragma unroll
      for (int n = 0; n < 2; ++n) {
        int d = n * 32 + c31;                 // 0..63
        #pragma unroll
        for (int j = 0; j < 16; ++j) {
          int s = s0 + (j & 3) + 8 * (j >> 2);
          float c  = cosT[s * 64 + d];
          float sn = sinT[s * 64 + d];
          float x0 = acc[m][n][j], x1 = acc[m][n + 2][j];
          dst_[(hbase + s) * 128 + d]      = (bf16_t)(x0 * c - x1 * sn);
          dst_[(hbase + s) * 128 + d + 64] = (bf16_t)(x1 * c + x0 * sn);
        }
      }
    }
  }
}

// ---------------- sparse flash attention (R15: 48KB split-stage) ------------
__global__ __launch_bounds__(512, 4) void attn_kernel(
    const bf16_t* __restrict__ Qf, const bf16_t* __restrict__ Kf,
    const bf16_t* __restrict__ Vt, const int* __restrict__ anchors,
    bf16_t* __restrict__ outB)   // [B,S,2048] bf16
{
  __shared__ bf16_t SH[24576];      // 48KB: Kl | Vl | P
  bf16_t* Kl = SH;                  // [64 tok][128 d] swizzled, 16KB
  bf16_t* Vl = SH + 8192;           // [128 d][64 tok] swizzled, 16KB
  bf16_t* Pb = SH + 16384;          // per-wave 2KB x 8
  const int orig = blockIdx.x;
  const int blk = (orig & 7) * 128 + (orig >> 3);   // XCD-chunked swizzle
  const int qt = 31 - (blk & 31);                   // long blocks first
  const int h = (blk >> 5) & 15, b = blk >> 9;
  const int bh = b * 16 + h;
  const int tid = threadIdx.x, w = tid >> 6, l = tid & 63;
  const int fr = l & 15, g4 = l >> 4;
  const float scale = 0.08838834764831845f;   // 1/sqrt(128)

  const int* anc = anchors + ((size_t)bh * 32 + qt) * 7;
  unsigned long long pk = 0;
  int nt = 0;
  #pragma unroll
  for (int t = 0; t < 7; ++t) {
    int v = anc[t];
    if (v <= qt) { pk |= (unsigned long long)v << (5 * nt); ++nt; }
  }
  pk |= (unsigned long long)qt << (5 * nt); ++nt;   // local tile last
  const int NS = nt * 2;

  const bf16_t* Qbase = Qf + (size_t)bh * 4096 * 128;
  const bf16_t* Kbase = Kf + (size_t)bh * 4096 * 128;
  const bf16_t* Vbase = Vt + (size_t)bh * 128 * 4096;
  char* P = (char*)(Pb + w * 1024);

  auto STAGE_K = [&](int tb2) {
    const bf16_t* ksrc = Kbase + (size_t)tb2 * 128;
    #pragma unroll
    for (int i = 0; i < 2; ++i) {
      int c = tid + i * 512;
      int kr = c >> 4, kcol = c & 15;
      async_copy16(ksrc + (size_t)kr * 128 + (size_t)((kcol ^ (kr & 7)) * 8),
                   (char*)Kl + c * 16);
    }
  };
  auto STAGE_V = [&](int tb2) {
    const bf16_t* vsrc = Vbase + tb2;
    #pragma unroll
    for (int i = 0; i < 2; ++i) {
      int c = tid + i * 512;
      int vr = c >> 3, vcol = c & 7;
      async_copy16(vsrc + (size_t)vr * 4096 + (size_t)((vcol ^ (vr & 7)) * 8),
                   (char*)Vl + c * 16);
    }
  };

  const int qrow = qt * 128 + w * 16 + fr;
  bf16x8 aq[4];
  #pragma unroll
  for (int kc = 0; kc < 4; ++kc)
    aq[kc] = *(const bf16x8*)(Qbase + (size_t)qrow * 128 + kc * 32 + g4 * 8);

  {
    int tb0 = (int)(pk & 31) * 128;
    STAGE_K(tb0);
    STAGE_V(tb0);
    asm volatile("s_waitcnt vmcnt(2)" ::: "memory");
    SBAR0(); __builtin_amdgcn_s_barrier(); SBAR0();
  }

  float mrun = -1e30f, lrun = 0.f;
  f32x4 o[8];
  #pragma unroll
  for (int nd = 0; nd < 8; ++nd) o[nd] = (f32x4){0.f, 0.f, 0.f, 0.f};

  for (int s = 0; s < NS; ++s) {
    const int ts = (int)((pk >> (5 * (s >> 1))) & 31);
    const bool domask = (ts == qt);
    const bool more = (s + 1 < NS);
    int ntb = 0;
    if (more) {
      int s1 = s + 1;
      ntb = (int)((pk >> (5 * (s1 >> 1))) & 31) * 128 + (s1 & 1) * 64;
    }

    f32x4 sc[4];
    #pragma unroll
    for (int n = 0; n < 4; ++n) sc[n] = (f32x4){0.f, 0.f, 0.f, 0.f};
    #pragma unroll
    for (int kc = 0; kc < 4; ++kc) {
      bf16x8 kf[4];
      #pragma unroll
      for (int n = 0; n < 4; ++n) {
        int r = n * 16 + fr;
        kf[n] = *(const bf16x8*)((const char*)Kl +
                 r * 256 + (((kc * 4 + g4) ^ (r & 7)) << 4));
      }
      #pragma unroll
      for (int n = 0; n < 4; ++n)
        sc[n] = mfma16x16x32(kf[n], aq[kc], sc[n]);
    }

    asm volatile("s_waitcnt vmcnt(0)" ::: "memory");
    SBAR0(); __builtin_amdgcn_s_barrier(); SBAR0();
    if (more) STAGE_K(ntb);        // flies under softmax + PV

    float rmax = -1e30f;
    if (domask) {
      const int qr = w * 16 + fr;
      #pragma unroll
      for (int n = 0; n < 4; ++n)
        #pragma unroll
        for (int j = 0; j < 4; ++j) {
          float lg = sc[n][j] * scale;
          int tok = (s & 1) * 64 + n * 16 + g4 * 4 + j;
          if (tok > qr) lg = -1e10f;
          sc[n][j] = lg;
          rmax = fmaxf(rmax, lg);
        }
    } else {
      #pragma unroll
      for (int n = 0; n < 4; ++n)
        #pragma unroll
        for (int j = 0; j < 4; ++j) {
          float lg = sc[n][j] * scale;
          sc[n][j] = lg;
          rmax = fmaxf(rmax, lg);
        }
    }
    rmax = fmaxf(rmax, __shfl_xor(rmax, 16));
    rmax = fmaxf(rmax, __shfl_xor(rmax, 32));
    if (__any(rmax > mrun + 8.f)) {          // defer-max (T13)
      float mnew = fmaxf(mrun, rmax);
      float alpha = __expf(mrun - mnew);
      lrun *= alpha;
      #pragma unroll
      for (int nd = 0; nd < 8; ++nd)
        #pragma unroll
        for (int j = 0; j < 4; ++j) o[nd][j] *= alpha;
      mrun = mnew;
    }
    float rsum = 0.f;
    #pragma unroll
    for (int n = 0; n < 4; ++n) {
      bf16x4 pkv;
      #pragma unroll
      for (int j = 0; j < 4; ++j) {
        float pe = __expf(sc[n][j] - mrun);
        rsum += pe;
        pkv[j] = (bf16_t)pe;
      }
      int off = fr * 128 + ((((n << 1) | (g4 >> 1)) ^ (fr & 7)) << 4) + ((g4 & 1) << 3);
      *(bf16x4*)(P + off) = pkv;
    }
    rsum += __shfl_xor(rsum, 16);
    rsum += __shfl_xor(rsum, 32);
    lrun += rsum;

    #pragma unroll
    for (int kc2 = 0; kc2 < 2; ++kc2) {
      bf16x8 av[8];
      #pragma unroll
      for (int nd = 0; nd < 8; ++nd) {
        int r = nd * 16 + fr;
        av[nd] = *(const bf16x8*)((const char*)Vl +
                  r * 128 + (((kc2 * 4 + g4) ^ (r & 7)) << 4));
      }
      bf16x8 bp = *(const bf16x8*)(P + fr * 128 + ((((kc2 << 2) | g4) ^ (fr & 7)) << 4));
      #pragma unroll
      for (int nd = 0; nd < 8; ++nd)
        o[nd] = mfma16x16x32(av[nd], bp, o[nd]);
    }

    SBAR0(); __builtin_amdgcn_s_barrier(); SBAR0();
    if (more) {
      STAGE_V(ntb);
      asm volatile("s_waitcnt vmcnt(2)" ::: "memory");   // K(s+1) landed
      SBAR0(); __builtin_amdgcn_s_barrier(); SBAR0();
    }
  }

  {
    char* E = (char*)SH + w * 4096;          // 8 waves x 4KB over Kl+Vl region
    float inv = 1.0f / lrun;
    #pragma unroll
    for (int nd = 0; nd < 8; ++nd) {
      bf16x4 pkv;
      #pragma unroll
      for (int j = 0; j < 4; ++j) pkv[j] = (bf16_t)(o[nd][j] * inv);
      int off = fr * 256 + ((((nd << 1) | (g4 >> 1)) ^ (fr & 7)) << 4) + ((g4 & 1) << 3);
      *(bf16x4*)(E + off) = pkv;
    }
    #pragma unroll
    for (int i = 0; i < 4; ++i) {
      int r = i * 4 + g4;
      int off = r * 256 + ((fr ^ (r & 7)) << 4);
      bf16x8 vrow = *(const bf16x8*)(E + off);
      size_t gaddr = (((size_t)b * 4096 + qt * 128 + w * 16 + r) * 2048)
                     + h * 128 + fr * 8;
      *(bf16x8*)(outB + gaddr) = vrow;
    }
  }
}

// ---------------------------------------------------------------------------
// workspace layout (bytes)
#define OFF_XB   ((size_t)0)            // x bf16            [8192][2048]  32MB
#define OFF_WCAT ((size_t)33554432)     // concat wq^T|wk^T|wv^T bf16 [6144][2048] 24MB
#define OFF_WOT  ((size_t)58720256)     // wo^T bf16 [2048][2048] 8MB
#define OFF_QF   ((size_t)67108864)     // Q bf16 [B,H,S,D]  32MB
#define OFF_KF   ((size_t)100663296)    // K bf16 [B,H,S,D]  32MB
#define OFF_AT   ((size_t)134217728)    // attn out [B,S,2048] bf16 32MB
#define OFF_VT   ((size_t)167772160)    // V^T bf16 [B,H,D,S] 32MB

extern "C" void kernel_launch(void* const* d_in, const int* in_sizes, int n_in,
                              void* d_out, int out_size, void* d_ws, size_t ws_size,
                              hipStream_t stream) {
  (void)in_sizes; (void)n_in; (void)out_size; (void)ws_size;
  const float* x    = (const float*)d_in[0];
  const float* wq   = (const float*)d_in[1];
  const float* wk   = (const float*)d_in[2];
  const float* wv   = (const float*)d_in[3];
  const float* wo   = (const float*)d_in[4];
  const float* cosT = (const float*)d_in[5];
  const float* sinT = (const float*)d_in[6];
  const int*   anc  = (const int*)d_in[7];
  float* out = (float*)d_out;
  char* ws = (char*)d_ws;

  bf16_t* xb   = (bf16_t*)(ws + OFF_XB);
  bf16_t* wcat = (bf16_t*)(ws + OFF_WCAT);
  bf16_t* wot  = (bf16_t*)(ws + OFF_WOT);
  bf16_t* Qf   = (bf16_t*)(ws + OFF_QF);
  bf16_t* Kf   = (bf16_t*)(ws + OFF_KF);
  bf16_t* Vt   = (bf16_t*)(ws + OFF_VT);
  bf16_t* attnB = (bf16_t*)(ws + OFF_AT);

  prep_kernel<<<20480, 256, 0, stream>>>(x, wq, wk, wv, wo, xb, wcat, wot);
  gemm256<<<768, 512, 0, stream>>>(xb, wcat, 24, 1, nullptr, Qf, Kf, Vt, cosT, sinT);
  attn_kernel<<<1024, 512, 0, stream>>>(Qf, Kf, Vt, anc, attnB);
  gemm256<<<256, 512, 0, stream>>>(attnB, wot, 8, 0, out, nullptr, nullptr, nullptr,
                                   nullptr, nullptr);
}

// Round 17
// 353.093 us; speedup vs baseline: 1.1222x; 1.1222x over previous
//
#include <hip/hip_runtime.h>
#include <hip/hip_bf16.h>

// ---------------------------------------------------------------------------
// KascadeReuseAttention: B=2,S=4096,H=16,D=128, TILE=128, T=32, TOPK=7(+local)
// R17 = R15 (session best, 351.4 us): GEMM 256x256 BK=64 2-slot 1-barrier
// (16x16x32 MFMA, M-fastest chunks, coalesced mode-0 store); attn 48KB
// split-stage pipeline; prep merged. R16's 32x32 MFMA reverted (18.9M bank
// conflicts from the 32-row fragment read pattern).
// ---------------------------------------------------------------------------

typedef __bf16 bf16_t;
using bf16x8 = __attribute__((ext_vector_type(8))) __bf16;
using bf16x4 = __attribute__((ext_vector_type(4))) __bf16;
using f32x4  = __attribute__((ext_vector_type(4))) float;

typedef const __attribute__((address_space(1))) void* gas_ptr;
typedef __attribute__((address_space(3))) void* las_ptr;

__device__ __forceinline__ void async_copy16(const void* g, void* l) {
  __builtin_amdgcn_global_load_lds((gas_ptr)g, (las_ptr)l, 16, 0, 0);
}

__device__ __forceinline__ f32x4 mfma16x16x32(bf16x8 a, bf16x8 b, f32x4 c) {
  return __builtin_amdgcn_mfma_f32_16x16x32_bf16(a, b, c, 0, 0, 0);
}

#define SBAR0() __builtin_amdgcn_sched_barrier(0)

// -------- prep: weight transpose x4 + x f32->bf16, one dispatch -------------
__global__ void prep_kernel(const float* __restrict__ x, const float* __restrict__ wq,
                            const float* __restrict__ wk, const float* __restrict__ wv,
                            const float* __restrict__ wo, bf16_t* __restrict__ xb,
                            bf16_t* __restrict__ wcat, bf16_t* __restrict__ wot) {
  __shared__ bf16_t t[64][66];
  const int bidx = blockIdx.x;
  if (bidx >= 4096) {
    int idx = (bidx - 4096) * 256 + threadIdx.x;
    float4 v = ((const float4*)x)[idx];
    bf16x4 r;
    r.x = (bf16_t)v.x; r.y = (bf16_t)v.y; r.z = (bf16_t)v.z; r.w = (bf16_t)v.w;
    ((bf16x4*)xb)[idx] = r;
    return;
  }
  const int z = bidx >> 10, bt = bidx & 1023;
  const float* W = (z == 0) ? wq : (z == 1) ? wk : (z == 2) ? wv : wo;
  bf16_t* Wt = (z == 3) ? wot : (wcat + (size_t)z * 2048 * 2048);
  const int r0 = (bt >> 5) * 64, c0 = (bt & 31) * 64;
  const int tx = threadIdx.x & 63, ty = threadIdx.x >> 6;
  #pragma unroll
  for (int i = 0; i < 16; ++i) {
    int r = ty + 4 * i;
    t[r][tx] = (bf16_t)W[(size_t)(r0 + r) * 2048 + c0 + tx];
  }
  __syncthreads();
  #pragma unroll
  for (int i = 0; i < 16; ++i) {
    int n = ty + 4 * i;
    Wt[(size_t)(c0 + n) * 2048 + r0 + tx] = t[tx][n];
  }
}

// ---------------- GEMM 256x256 pipelined (best measured) --------------------
// 8 waves as 4M x 2N (per-wave 64Mx128N; full head span in-thread for rope).
// LDS: 2-slot double buffer of A[256][64]+B[256][64] bf16 panels (128KiB).
// Swizzle: rows are 8 x 16B chunks; LDS[row][ch] = global[row][ch^(row&7)].
// Phase phi (32, BK=64): {kc0 frags | STAGE(phi+1) | kc0 MFMA x32 | kc1 frags
// | kc1 MFMA x32 | vmcnt(0) | raw s_barrier}.
// Block map: XCD chunk of cpx blocks; within chunk M varies fastest.
// mode 0: f32 C row-major (nb=8), stores coalesced via per-wave LDS scratch.
// mode 1: fused QKV (nb=24): Q,K rope'd bf16 [B,H,S,D]; V -> V^T [B,H,D,S].
__global__ __launch_bounds__(512, 2) void gemm256(
    const bf16_t* __restrict__ A, const bf16_t* __restrict__ Bt,
    int nb, int mode, float* __restrict__ Cf,
    bf16_t* __restrict__ outQ, bf16_t* __restrict__ outK,
    bf16_t* __restrict__ outVT,
    const float* __restrict__ cosT, const float* __restrict__ sinT)
{
  __shared__ bf16_t Apan[2][16384];   // [256 rows][64 k] bf16 = 32KB per slot
  __shared__ bf16_t Bpan[2][16384];
  const int bid = blockIdx.x;
  const int cpx = gridDim.x >> 3;
  const int swz = (bid & 7) * cpx + (bid >> 3);   // XCD-chunked (grid%8==0)
  const int RM = cpx / nb;                        // M-rows per chunk
  const int bm = ((swz / cpx) * RM + (swz % RM)) * 256;   // M fastest in chunk
  const int bn = ((swz % cpx) / RM) * 256;
  const int tid = threadIdx.x;
  const int w = tid >> 6, l = tid & 63;
  const int wr = w >> 1, wc = w & 1;              // 4M x 2N
  const int fr = l & 15, g4 = l >> 4;

  const bf16_t* aS[4];
  const bf16_t* bS[4];
  int dst[4];
  #pragma unroll
  for (int i = 0; i < 4; ++i) {
    int c = tid + i * 512;
    int row = c >> 3, ch = c & 7;
    int sc = (ch ^ (row & 7)) * 8;
    aS[i] = A  + (size_t)(bm + row) * 2048 + sc;
    bS[i] = Bt + (size_t)(bn + row) * 2048 + sc;
    dst[i] = c * 16;
  }

  int aOff[2][4], bOff[2][8];
  #pragma unroll
  for (int kc = 0; kc < 2; ++kc) {
    #pragma unroll
    for (int m = 0; m < 4; ++m) {
      int R = wr * 64 + m * 16 + fr;
      aOff[kc][m] = R * 128 + (((kc * 4 + g4) ^ (R & 7)) << 4);
    }
    #pragma unroll
    for (int n = 0; n < 8; ++n) {
      int R = wc * 128 + n * 16 + fr;
      bOff[kc][n] = R * 128 + (((kc * 4 + g4) ^ (R & 7)) << 4);
    }
  }

  f32x4 acc[4][8];
  #pragma unroll
  for (int m = 0; m < 4; ++m)
    #pragma unroll
    for (int n = 0; n < 8; ++n) acc[m][n] = (f32x4){0.f, 0.f, 0.f, 0.f};

  auto STAGE = [&](int t) {        // stage K-tile t (64 wide) into slot t&1
    const int slot = t & 1;
    const int kb = t * 64;
    char* dA = (char*)&Apan[slot][0];
    char* dB = (char*)&Bpan[slot][0];
    #pragma unroll
    for (int i = 0; i < 4; ++i) {
      async_copy16(aS[i] + kb, dA + dst[i]);
      async_copy16(bS[i] + kb, dB + dst[i]);
    }
  };

  STAGE(0);
  __syncthreads();   // prologue: tile 0 landed (full drain, once)

  #pragma unroll 1
  for (int phi = 0; phi < 32; ++phi) {
    const int slot = phi & 1;
    const char* pa = (const char*)&Apan[slot][0];
    const char* pb = (const char*)&Bpan[slot][0];

    bf16x8 af0[4], bf0[8];
    #pragma unroll
    for (int m = 0; m < 4; ++m) af0[m] = *(const bf16x8*)(pa + aOff[0][m]);
    #pragma unroll
    for (int n = 0; n < 8; ++n) bf0[n] = *(const bf16x8*)(pb + bOff[0][n]);
    if (phi < 31) STAGE(phi + 1);
    __builtin_amdgcn_s_setprio(1);
    #pragma unroll
    for (int m = 0; m < 4; ++m)
      #pragma unroll
      for (int n = 0; n < 8; ++n)
        acc[m][n] = mfma16x16x32(af0[m], bf0[n], acc[m][n]);
    __builtin_amdgcn_s_setprio(0);

    bf16x8 af1[4], bf1[8];
    #pragma unroll
    for (int m = 0; m < 4; ++m) af1[m] = *(const bf16x8*)(pa + aOff[1][m]);
    #pragma unroll
    for (int n = 0; n < 8; ++n) bf1[n] = *(const bf16x8*)(pb + bOff[1][n]);
    __builtin_amdgcn_s_setprio(1);
    #pragma unroll
    for (int m = 0; m < 4; ++m)
      #pragma unroll
      for (int n = 0; n < 8; ++n)
        acc[m][n] = mfma16x16x32(af1[m], bf1[n], acc[m][n]);
    __builtin_amdgcn_s_setprio(0);

    asm volatile("s_waitcnt vmcnt(0)" ::: "memory");
    SBAR0();
    __builtin_amdgcn_s_barrier();
    SBAR0();
  }

  if (mode == 0) {
    // coalesced f32 store via per-wave 16KB LDS scratch (panels dead)
    float* S = (w < 4) ? (float*)((char*)&Apan[0][0] + w * 16384)
                       : (float*)((char*)&Bpan[0][0] + (w - 4) * 16384);
    #pragma unroll
    for (int h = 0; h < 2; ++h) {
      #pragma unroll
      for (int mm = 0; mm < 2; ++mm) {
        int m = h * 2 + mm;
        #pragma unroll
        for (int n = 0; n < 8; ++n)
          #pragma unroll
          for (int j = 0; j < 4; ++j)
            S[(mm * 16 + g4 * 4 + j) * 128 + n * 16 + fr] = acc[m][n][j];
      }
      #pragma unroll
      for (int r2 = 0; r2 < 32; ++r2) {
        float2 v = *(const float2*)&S[r2 * 128 + l * 2];
        int row = bm + wr * 64 + h * 32 + r2;
        *(float2*)&Cf[(size_t)row * 2048 + bn + wc * 128 + l * 2] = v;
      }
    }
    return;
  }

  // ---- fused QKV epilogue ----
  const int colbase = bn + wc * 128;
  const int proj = colbase >> 11;             // 0=Q 1=K 2=V
  const int hh = (colbase & 2047) >> 7;
  if (proj == 2) {
    #pragma unroll
    for (int m = 0; m < 4; ++m) {
      int row0 = bm + wr * 64 + m * 16 + g4 * 4;
      int b_ = row0 >> 12, sr = row0 & 4095;
      #pragma unroll
      for (int n = 0; n < 8; ++n) {
        int d_ = n * 16 + fr;
        bf16x4 pkv;
        #pragma unroll
        for (int j = 0; j < 4; ++j) pkv[j] = (bf16_t)acc[m][n][j];
        *(bf16x4*)&outVT[(((size_t)(b_ * 16 + hh)) * 128 + d_) * 4096 + sr] = pkv;
      }
    }
  } else {
    bf16_t* dst_ = proj ? outK : outQ;
    #pragma unroll
    for (int m = 0; m < 4; ++m) {
      int row0 = bm + wr * 64 + m * 16 + g4 * 4;
      int b_ = row0 >> 12, s0 = row0 & 4095;
      size_t hbase = ((size_t)(b_ * 16 + hh)) * 4096;
      #pragma unroll
      for (int n = 0; n < 4; ++n) {
        int d = n * 16 + fr;
        #pragma unroll
        for (int j = 0; j < 4; ++j) {
          int s = s0 + j;
          float c  = cosT[s * 64 + d];
          float sn = sinT[s * 64 + d];
          float x0 = acc[m][n][j], x1 = acc[m][n + 4][j];
          dst_[(hbase + s) * 128 + d]      = (bf16_t)(x0 * c - x1 * sn);
          dst_[(hbase + s) * 128 + d + 64] = (bf16_t)(x1 * c + x0 * sn);
        }
      }
    }
  }
}

// ---------------- sparse flash attention (48KB split-stage pipeline) --------
// block = (b,h,qt): 512 threads, 8 waves x 16 q-rows. LDS 48KB:
// Kl [64][128] 16KB | Vl [128][64] 16KB | P 8x2KB.
// Step s: QK(s) | vmcnt(0) [V(s) landed] bar1 [Kl free] | stage K(s+1) |
// softmax+PV(s) | bar2 [Vl free] | stage V(s+1) | vmcnt(2) [K(s+1) landed]
// bar3. Active tiles only (tsel<=qt); mask only local; defer-max (T13).
__global__ __launch_bounds__(512, 4) void attn_kernel(
    const bf16_t* __restrict__ Qf, const bf16_t* __restrict__ Kf,
    const bf16_t* __restrict__ Vt, const int* __restrict__ anchors,
    bf16_t* __restrict__ outB)   // [B,S,2048] bf16
{
  __shared__ bf16_t SH[24576];      // 48KB: Kl | Vl | P
  bf16_t* Kl = SH;                  // [64 tok][128 d] swizzled, 16KB
  bf16_t* Vl = SH + 8192;           // [128 d][64 tok] swizzled, 16KB
  bf16_t* Pb = SH + 16384;          // per-wave 2KB x 8
  const int orig = blockIdx.x;
  const int blk = (orig & 7) * 128 + (orig >> 3);   // XCD-chunked swizzle
  const int qt = 31 - (blk & 31);                   // long blocks first
  const int h = (blk >> 5) & 15, b = blk >> 9;
  const int bh = b * 16 + h;
  const int tid = threadIdx.x, w = tid >> 6, l = tid & 63;
  const int fr = l & 15, g4 = l >> 4;
  const float scale = 0.08838834764831845f;   // 1/sqrt(128)

  const int* anc = anchors + ((size_t)bh * 32 + qt) * 7;
  unsigned long long pk = 0;
  int nt = 0;
  #pragma unroll
  for (int t = 0; t < 7; ++t) {
    int v = anc[t];
    if (v <= qt) { pk |= (unsigned long long)v << (5 * nt); ++nt; }
  }
  pk |= (unsigned long long)qt << (5 * nt); ++nt;   // local tile last
  const int NS = nt * 2;

  const bf16_t* Qbase = Qf + (size_t)bh * 4096 * 128;
  const bf16_t* Kbase = Kf + (size_t)bh * 4096 * 128;
  const bf16_t* Vbase = Vt + (size_t)bh * 128 * 4096;
  char* P = (char*)(Pb + w * 1024);

  auto STAGE_K = [&](int tb2) {
    const bf16_t* ksrc = Kbase + (size_t)tb2 * 128;
    #pragma unroll
    for (int i = 0; i < 2; ++i) {
      int c = tid + i * 512;
      int kr = c >> 4, kcol = c & 15;
      async_copy16(ksrc + (size_t)kr * 128 + (size_t)((kcol ^ (kr & 7)) * 8),
                   (char*)Kl + c * 16);
    }
  };
  auto STAGE_V = [&](int tb2) {
    const bf16_t* vsrc = Vbase + tb2;
    #pragma unroll
    for (int i = 0; i < 2; ++i) {
      int c = tid + i * 512;
      int vr = c >> 3, vcol = c & 7;
      async_copy16(vsrc + (size_t)vr * 4096 + (size_t)((vcol ^ (vr & 7)) * 8),
                   (char*)Vl + c * 16);
    }
  };

  const int qrow = qt * 128 + w * 16 + fr;
  bf16x8 aq[4];
  #pragma unroll
  for (int kc = 0; kc < 4; ++kc)
    aq[kc] = *(const bf16x8*)(Qbase + (size_t)qrow * 128 + kc * 32 + g4 * 8);

  {
    int tb0 = (int)(pk & 31) * 128;
    STAGE_K(tb0);
    STAGE_V(tb0);
    asm volatile("s_waitcnt vmcnt(2)" ::: "memory");
    SBAR0(); __builtin_amdgcn_s_barrier(); SBAR0();
  }

  float mrun = -1e30f, lrun = 0.f;
  f32x4 o[8];
  #pragma unroll
  for (int nd = 0; nd < 8; ++nd) o[nd] = (f32x4){0.f, 0.f, 0.f, 0.f};

  for (int s = 0; s < NS; ++s) {
    const int ts = (int)((pk >> (5 * (s >> 1))) & 31);
    const bool domask = (ts == qt);
    const bool more = (s + 1 < NS);
    int ntb = 0;
    if (more) {
      int s1 = s + 1;
      ntb = (int)((pk >> (5 * (s1 >> 1))) & 31) * 128 + (s1 & 1) * 64;
    }

    f32x4 sc[4];
    #pragma unroll
    for (int n = 0; n < 4; ++n) sc[n] = (f32x4){0.f, 0.f, 0.f, 0.f};
    #pragma unroll
    for (int kc = 0; kc < 4; ++kc) {
      bf16x8 kf[4];
      #pragma unroll
      for (int n = 0; n < 4; ++n) {
        int r = n * 16 + fr;
        kf[n] = *(const bf16x8*)((const char*)Kl +
                 r * 256 + (((kc * 4 + g4) ^ (r & 7)) << 4));
      }
      #pragma unroll
      for (int n = 0; n < 4; ++n)
        sc[n] = mfma16x16x32(kf[n], aq[kc], sc[n]);
    }

    asm volatile("s_waitcnt vmcnt(0)" ::: "memory");
    SBAR0(); __builtin_amdgcn_s_barrier(); SBAR0();
    if (more) STAGE_K(ntb);        // flies under softmax + PV

    float rmax = -1e30f;
    if (domask) {
      const int qr = w * 16 + fr;
      #pragma unroll
      for (int n = 0; n < 4; ++n)
        #pragma unroll
        for (int j = 0; j < 4; ++j) {
          float lg = sc[n][j] * scale;
          int tok = (s & 1) * 64 + n * 16 + g4 * 4 + j;
          if (tok > qr) lg = -1e10f;
          sc[n][j] = lg;
          rmax = fmaxf(rmax, lg);
        }
    } else {
      #pragma unroll
      for (int n = 0; n < 4; ++n)
        #pragma unroll
        for (int j = 0; j < 4; ++j) {
          float lg = sc[n][j] * scale;
          sc[n][j] = lg;
          rmax = fmaxf(rmax, lg);
        }
    }
    rmax = fmaxf(rmax, __shfl_xor(rmax, 16));
    rmax = fmaxf(rmax, __shfl_xor(rmax, 32));
    if (__any(rmax > mrun + 8.f)) {          // defer-max (T13)
      float mnew = fmaxf(mrun, rmax);
      float alpha = __expf(mrun - mnew);
      lrun *= alpha;
      #pragma unroll
      for (int nd = 0; nd < 8; ++nd)
        #pragma unroll
        for (int j = 0; j < 4; ++j) o[nd][j] *= alpha;
      mrun = mnew;
    }
    float rsum = 0.f;
    #pragma unroll
    for (int n = 0; n < 4; ++n) {
      bf16x4 pkv;
      #pragma unroll
      for (int j = 0; j < 4; ++j) {
        float pe = __expf(sc[n][j] - mrun);
        rsum += pe;
        pkv[j] = (bf16_t)pe;
      }
      int off = fr * 128 + ((((n << 1) | (g4 >> 1)) ^ (fr & 7)) << 4) + ((g4 & 1) << 3);
      *(bf16x4*)(P + off) = pkv;
    }
    rsum += __shfl_xor(rsum, 16);
    rsum += __shfl_xor(rsum, 32);
    lrun += rsum;

    #pragma unroll
    for (int kc2 = 0; kc2 < 2; ++kc2) {
      bf16x8 av[8];
      #pragma unroll
      for (int nd = 0; nd < 8; ++nd) {
        int r = nd * 16 + fr;
        av[nd] = *(const bf16x8*)((const char*)Vl +
                  r * 128 + (((kc2 * 4 + g4) ^ (r & 7)) << 4));
      }
      bf16x8 bp = *(const bf16x8*)(P + fr * 128 + ((((kc2 << 2) | g4) ^ (fr & 7)) << 4));
      #pragma unroll
      for (int nd = 0; nd < 8; ++nd)
        o[nd] = mfma16x16x32(av[nd], bp, o[nd]);
    }

    SBAR0(); __builtin_amdgcn_s_barrier(); SBAR0();
    if (more) {
      STAGE_V(ntb);
      asm volatile("s_waitcnt vmcnt(2)" ::: "memory");   // K(s+1) landed
      SBAR0(); __builtin_amdgcn_s_barrier(); SBAR0();
    }
  }

  {
    char* E = (char*)SH + w * 4096;          // 8 waves x 4KB over Kl+Vl region
    float inv = 1.0f / lrun;
    #pragma unroll
    for (int nd = 0; nd < 8; ++nd) {
      bf16x4 pkv;
      #pragma unroll
      for (int j = 0; j < 4; ++j) pkv[j] = (bf16_t)(o[nd][j] * inv);
      int off = fr * 256 + ((((nd << 1) | (g4 >> 1)) ^ (fr & 7)) << 4) + ((g4 & 1) << 3);
      *(bf16x4*)(E + off) = pkv;
    }
    #pragma unroll
    for (int i = 0; i < 4; ++i) {
      int r = i * 4 + g4;
      int off = r * 256 + ((fr ^ (r & 7)) << 4);
      bf16x8 vrow = *(const bf16x8*)(E + off);
      size_t gaddr = (((size_t)b * 4096 + qt * 128 + w * 16 + r) * 2048)
                     + h * 128 + fr * 8;
      *(bf16x8*)(outB + gaddr) = vrow;
    }
  }
}

// ---------------------------------------------------------------------------
// workspace layout (bytes)
#define OFF_XB   ((size_t)0)            // x bf16            [8192][2048]  32MB
#define OFF_WCAT ((size_t)33554432)     // concat wq^T|wk^T|wv^T bf16 [6144][2048] 24MB
#define OFF_WOT  ((size_t)58720256)     // wo^T bf16 [2048][2048] 8MB
#define OFF_QF   ((size_t)67108864)     // Q bf16 [B,H,S,D]  32MB
#define OFF_KF   ((size_t)100663296)    // K bf16 [B,H,S,D]  32MB
#define OFF_AT   ((size_t)134217728)    // attn out [B,S,2048] bf16 32MB
#define OFF_VT   ((size_t)167772160)    // V^T bf16 [B,H,D,S] 32MB

extern "C" void kernel_launch(void* const* d_in, const int* in_sizes, int n_in,
                              void* d_out, int out_size, void* d_ws, size_t ws_size,
                              hipStream_t stream) {
  (void)in_sizes; (void)n_in; (void)out_size; (void)ws_size;
  const float* x    = (const float*)d_in[0];
  const float* wq   = (const float*)d_in[1];
  const float* wk   = (const float*)d_in[2];
  const float* wv   = (const float*)d_in[3];
  const float* wo   = (const float*)d_in[4];
  const float* cosT = (const float*)d_in[5];
  const float* sinT = (const float*)d_in[6];
  const int*   anc  = (const int*)d_in[7];
  float* out = (float*)d_out;
  char* ws = (char*)d_ws;

  bf16_t* xb   = (bf16_t*)(ws + OFF_XB);
  bf16_t* wcat = (bf16_t*)(ws + OFF_WCAT);
  bf16_t* wot  = (bf16_t*)(ws + OFF_WOT);
  bf16_t* Qf   = (bf16_t*)(ws + OFF_QF);
  bf16_t* Kf   = (bf16_t*)(ws + OFF_KF);
  bf16_t* Vt   = (bf16_t*)(ws + OFF_VT);
  bf16_t* attnB = (bf16_t*)(ws + OFF_AT);

  prep_kernel<<<20480, 256, 0, stream>>>(x, wq, wk, wv, wo, xb, wcat, wot);
  gemm256<<<768, 512, 0, stream>>>(xb, wcat, 24, 1, nullptr, Qf, Kf, Vt, cosT, sinT);
  attn_kernel<<<1024, 512, 0, stream>>>(Qf, Kf, Vt, anc, attnB);
  gemm256<<<256, 512, 0, stream>>>(attnB, wot, 8, 0, out, nullptr, nullptr, nullptr,
                                   nullptr, nullptr);
}